// Round 8
// baseline (561.944 us; speedup 1.0000x reference)
//
#include <hip/hip_runtime.h>

#define B_ 2
#define L_ 1024
#define D_ 1024
#define H_ 6
#define DK_ 128
#define DV_ 256
#define KD_ 768
#define VD_ 1536
#define KS_ 4
#define KD2_ 1536   // merged q|k projection width
#define VD2_ 3072   // merged v|g projection width

using bf16x8 = __attribute__((ext_vector_type(8))) short;
using u16x8 = __attribute__((ext_vector_type(8))) unsigned short;
using f32x4 = __attribute__((ext_vector_type(4))) float;

__device__ __forceinline__ float silu_f(float x) { return x / (1.0f + expf(-x)); }

__device__ __forceinline__ unsigned short f2bf(float f) {
  unsigned int u = __float_as_uint(f);
  u = (u + 0x7fffu + ((u >> 16) & 1u)) >> 16;
  return (unsigned short)u;
}

__device__ __forceinline__ void gl_lds16(const void* g, void* l) {
  __builtin_amdgcn_global_load_lds((const __attribute__((address_space(1))) unsigned int*)g,
                                   (__attribute__((address_space(3))) unsigned int*)l, 16, 0, 0);
}
__device__ __forceinline__ void gl_lds4(const void* g, void* l) {
  __builtin_amdgcn_global_load_lds((const __attribute__((address_space(1))) unsigned int*)g,
                                   (__attribute__((address_space(3))) unsigned int*)l, 4, 0, 0);
}

template <int CTRL>
__device__ __forceinline__ float dpp_add(float x) {
  int y = __builtin_amdgcn_mov_dpp(__float_as_int(x), CTRL, 0xF, 0xF, true);
  return x + __int_as_float(y);
}
// full 16-lane-group sum via DPP butterfly: masks {1,2,7,15} span {0..15}
__device__ __forceinline__ float red16(float x) {
  x = dpp_add<0xB1>(x);   // quad_perm xor 1
  x = dpp_add<0x4E>(x);   // quad_perm xor 2
  x = dpp_add<0x141>(x);  // row_half_mirror xor 7
  x = dpp_add<0x140>(x);  // row_mirror xor 15
  return x;
}

// ---------------------------------------------------------------------------
// fp32 SGEMM (used once: merged Wb|Wa, N=12)
// ---------------------------------------------------------------------------
__global__ __launch_bounds__(256) void sgemm64(const float* __restrict__ A,
                                               const float* __restrict__ Bm,
                                               float* __restrict__ C,
                                               int M, int N, int K) {
  __shared__ float As[16][64];
  __shared__ float Bs[16][64];
  const int tid = threadIdx.x;
  const int bx = blockIdx.x, by = blockIdx.y;
  const int tx = tid & 15, ty = tid >> 4;
  const int m0 = by * 64, n0 = bx * 64;
  const int ar = tid >> 2, ac = (tid & 3) << 2;
  const int br = tid >> 4, bc = (tid & 15) << 2;
  const bool n4 = ((N & 3) == 0);
  float acc[4][4];
#pragma unroll
  for (int i = 0; i < 4; i++)
#pragma unroll
    for (int j = 0; j < 4; j++) acc[i][j] = 0.0f;

  for (int k0 = 0; k0 < K; k0 += 16) {
    float4 av = *reinterpret_cast<const float4*>(A + (size_t)(m0 + ar) * K + (k0 + ac));
    As[ac + 0][ar] = av.x;
    As[ac + 1][ar] = av.y;
    As[ac + 2][ar] = av.z;
    As[ac + 3][ar] = av.w;
    float4 bv;
    if (n4 && (n0 + bc + 3 < N)) {
      bv = *reinterpret_cast<const float4*>(Bm + (size_t)(k0 + br) * N + (n0 + bc));
    } else {
      bv.x = (n0 + bc + 0 < N) ? Bm[(size_t)(k0 + br) * N + (n0 + bc + 0)] : 0.0f;
      bv.y = (n0 + bc + 1 < N) ? Bm[(size_t)(k0 + br) * N + (n0 + bc + 1)] : 0.0f;
      bv.z = (n0 + bc + 2 < N) ? Bm[(size_t)(k0 + br) * N + (n0 + bc + 2)] : 0.0f;
      bv.w = (n0 + bc + 3 < N) ? Bm[(size_t)(k0 + br) * N + (n0 + bc + 3)] : 0.0f;
    }
    Bs[br][bc + 0] = bv.x;
    Bs[br][bc + 1] = bv.y;
    Bs[br][bc + 2] = bv.z;
    Bs[br][bc + 3] = bv.w;
    __syncthreads();
#pragma unroll
    for (int kk = 0; kk < 16; kk++) {
      float4 a = *reinterpret_cast<const float4*>(&As[kk][ty << 2]);
      float4 b = *reinterpret_cast<const float4*>(&Bs[kk][tx << 2]);
      acc[0][0] = fmaf(a.x, b.x, acc[0][0]);
      acc[0][1] = fmaf(a.x, b.y, acc[0][1]);
      acc[0][2] = fmaf(a.x, b.z, acc[0][2]);
      acc[0][3] = fmaf(a.x, b.w, acc[0][3]);
      acc[1][0] = fmaf(a.y, b.x, acc[1][0]);
      acc[1][1] = fmaf(a.y, b.y, acc[1][1]);
      acc[1][2] = fmaf(a.y, b.z, acc[1][2]);
      acc[1][3] = fmaf(a.y, b.w, acc[1][3]);
      acc[2][0] = fmaf(a.z, b.x, acc[2][0]);
      acc[2][1] = fmaf(a.z, b.y, acc[2][1]);
      acc[2][2] = fmaf(a.z, b.z, acc[2][2]);
      acc[2][3] = fmaf(a.z, b.w, acc[2][3]);
      acc[3][0] = fmaf(a.w, b.x, acc[3][0]);
      acc[3][1] = fmaf(a.w, b.y, acc[3][1]);
      acc[3][2] = fmaf(a.w, b.z, acc[3][2]);
      acc[3][3] = fmaf(a.w, b.w, acc[3][3]);
    }
    __syncthreads();
  }
#pragma unroll
  for (int i = 0; i < 4; i++) {
    int m = m0 + (ty << 2) + i;
#pragma unroll
    for (int j = 0; j < 4; j++) {
      int n = n0 + (tx << 2) + j;
      if (n < N) C[(size_t)m * N + n] = acc[i][j];
    }
  }
}

// ---------------------------------------------------------------------------
__global__ void cast_bf16_kernel(const float* __restrict__ in, unsigned short* __restrict__ out,
                                 int n4) {
  int i = blockIdx.x * 256 + threadIdx.x;
  if (i >= n4) return;
  float4 v = *reinterpret_cast<const float4*>(in + (size_t)i * 4);
  ushort4 o;
  o.x = f2bf(v.x);
  o.y = f2bf(v.y);
  o.z = f2bf(v.z);
  o.w = f2bf(v.w);
  *reinterpret_cast<ushort4*>(out + (size_t)i * 4) = o;
}

// ---------------------------------------------------------------------------
// transpose + cast: W fp32 [K][N] -> Wt bf16 [N][K].  64x64 tiles.
// ---------------------------------------------------------------------------
__global__ __launch_bounds__(256) void tcast_kernel(const float* __restrict__ W,
                                                    unsigned short* __restrict__ Wt,
                                                    int K, int N) {
  __shared__ unsigned short T[64][72];
  const int tid = threadIdx.x;
  const int k0 = blockIdx.y * 64, n0 = blockIdx.x * 64;
  const int c4 = (tid & 15) * 4, r = tid >> 4;
#pragma unroll
  for (int j = 0; j < 4; j++) {
    int row = r + j * 16;
    float4 w = *reinterpret_cast<const float4*>(W + (size_t)(k0 + row) * N + n0 + c4);
    T[c4 + 0][row] = f2bf(w.x);
    T[c4 + 1][row] = f2bf(w.y);
    T[c4 + 2][row] = f2bf(w.z);
    T[c4 + 3][row] = f2bf(w.w);
  }
  __syncthreads();
#pragma unroll
  for (int j = 0; j < 4; j++) {
    int nr = r + j * 16;
    ushort4 o;
    o.x = T[nr][c4 + 0];
    o.y = T[nr][c4 + 1];
    o.z = T[nr][c4 + 2];
    o.w = T[nr][c4 + 3];
    *reinterpret_cast<ushort4*>(Wt + (size_t)(n0 + nr) * K + k0 + c4) = o;
  }
}

// ---------------------------------------------------------------------------
// bf16 MFMA GEMM (m97 structure, gl_lds staging, involution chunk-XOR)
// ---------------------------------------------------------------------------
__global__ __launch_bounds__(256) void mfma_gemm(const unsigned short* __restrict__ A,
                                                 const unsigned short* __restrict__ Bt,
                                                 float* __restrict__ C,
                                                 int M, int N, int K) {
  __shared__ __attribute__((aligned(16))) unsigned short As[128][32];
  __shared__ __attribute__((aligned(16))) unsigned short Bs[128][32];
  const int tid = threadIdx.x;
  const int wave = tid >> 6, lane = tid & 63;
  const int wm = wave >> 1, wn = wave & 1;
  const int m0 = blockIdx.y * 128, n0 = blockIdx.x * 128;
  const int lrow = lane >> 4;
  const int lcol = lane & 15;
  const int sr = lane >> 2;
  const int sc = lane & 3;

  f32x4 acc[4][4];
#pragma unroll
  for (int i = 0; i < 4; i++)
#pragma unroll
    for (int j = 0; j < 4; j++) acc[i][j] = f32x4{0.f, 0.f, 0.f, 0.f};

  const int Ra = wave * 32;

  for (int k0 = 0; k0 < K; k0 += 32) {
#pragma unroll
    for (int half = 0; half < 2; half++) {
      int r = Ra + half * 16 + sr;
      int ch = sc ^ ((r >> 1) & 3);
      gl_lds16(A + (size_t)(m0 + r) * K + k0 + ch * 8, &As[Ra + half * 16][0]);
      gl_lds16(Bt + (size_t)(n0 + r) * K + k0 + ch * 8, &Bs[Ra + half * 16][0]);
    }
    __syncthreads();
    bf16x8 af[4], bfr[4];
#pragma unroll
    for (int mr = 0; mr < 4; mr++) {
      int row = wm * 64 + mr * 16 + lcol;
      af[mr] = *reinterpret_cast<const bf16x8*>(&As[row][(lrow ^ ((row >> 1) & 3)) * 8]);
    }
#pragma unroll
    for (int nr = 0; nr < 4; nr++) {
      int row = wn * 64 + nr * 16 + lcol;
      bfr[nr] = *reinterpret_cast<const bf16x8*>(&Bs[row][(lrow ^ ((row >> 1) & 3)) * 8]);
    }
#pragma unroll
    for (int mr = 0; mr < 4; mr++)
#pragma unroll
      for (int nr = 0; nr < 4; nr++)
        acc[mr][nr] = __builtin_amdgcn_mfma_f32_16x16x32_bf16(af[mr], bfr[nr], acc[mr][nr], 0, 0, 0);
    __syncthreads();
  }

#pragma unroll
  for (int mr = 0; mr < 4; mr++) {
    int row = m0 + wm * 64 + mr * 16 + lrow * 4;
#pragma unroll
    for (int nr = 0; nr < 4; nr++) {
      int col = n0 + wn * 64 + nr * 16 + lcol;
#pragma unroll
      for (int r = 0; r < 4; r++) C[(size_t)(row + r) * N + col] = acc[mr][nr][r];
    }
  }
}

// ---------------------------------------------------------------------------
// concat Wb|Wa -> Wba[1024][12]
// ---------------------------------------------------------------------------
__global__ void concat_ba_kernel(const float* __restrict__ Wb, const float* __restrict__ Wa,
                                 float* __restrict__ Wba) {
  int i = blockIdx.x * 256 + threadIdx.x;
  if (i >= D_ * 12) return;
  int k = i / 12, j = i % 12;
  Wba[i] = (j < 6) ? Wb[k * 6 + j] : Wa[k * 6 + (j - 6)];
}

// ---------------------------------------------------------------------------
// beta / decay from merged yba[M][12]  (cols 0-5: yb, 6-11: ya)
// ---------------------------------------------------------------------------
__global__ void ba_kernel(const float* __restrict__ yba,
                          const float* __restrict__ A_log, const float* __restrict__ dt_bias,
                          float* __restrict__ beta_t, float* __restrict__ eg_t) {
  int i = blockIdx.x * 256 + threadIdx.x;
  if (i >= B_ * L_ * H_) return;
  int h = i % H_, bl = i / H_;
  int l = bl % L_, b = bl / L_;
  float yb = yba[(size_t)bl * 12 + h];
  float ya = yba[(size_t)bl * 12 + 6 + h];
  float beta = 1.0f / (1.0f + expf(-yb));
  float z = ya + dt_bias[h];
  float sp = (z > 20.0f) ? z : log1pf(expf(z));
  float g = -expf(A_log[h]) * sp;
  size_t o = ((size_t)b * H_ + h) * L_ + l;
  beta_t[o] = beta;
  eg_t[o] = expf(g);
}

// ---------------------------------------------------------------------------
// causal conv(4) + SiLU + L2-norm for q,k (from merged yqk[M][1536])
// ---------------------------------------------------------------------------
__global__ __launch_bounds__(256) void conv_qk_kernel(
    const float* __restrict__ yqk,
    const float* __restrict__ cwq, const float* __restrict__ cwk,
    float* __restrict__ qhat, float* __restrict__ khat) {
  const int lane = threadIdx.x & 63;
  const int widx = (blockIdx.x << 2) + (threadIdx.x >> 6);
  const int h = widx % H_;
  const int bl = widx / H_;
  const int l = bl % L_;
  const int b = bl / L_;
  const int ch = lane << 1;
  const int gc = h * DK_ + ch;

  float wq0[KS_], wq1[KS_], wk0[KS_], wk1[KS_];
#pragma unroll
  for (int j = 0; j < KS_; j++) {
    wq0[j] = cwq[(size_t)gc * KS_ + j];
    wq1[j] = cwq[(size_t)(gc + 1) * KS_ + j];
    wk0[j] = cwk[(size_t)gc * KS_ + j];
    wk1[j] = cwk[(size_t)(gc + 1) * KS_ + j];
  }
  float aq0 = 0, aq1 = 0, ak0 = 0, ak1 = 0;
#pragma unroll
  for (int j = 0; j < KS_; j++) {
    int ll = l - (KS_ - 1) + j;
    if (ll >= 0) {
      const size_t off = (size_t)(b * L_ + ll) * KD2_ + gc;
      float2 tq = *reinterpret_cast<const float2*>(yqk + off);
      float2 tk = *reinterpret_cast<const float2*>(yqk + off + 768);
      aq0 = fmaf(tq.x, wq0[j], aq0);
      aq1 = fmaf(tq.y, wq1[j], aq1);
      ak0 = fmaf(tk.x, wk0[j], ak0);
      ak1 = fmaf(tk.y, wk1[j], ak1);
    }
  }
  float q0 = silu_f(aq0), q1 = silu_f(aq1);
  float k0v = silu_f(ak0), k1v = silu_f(ak1);
  float ssq = q0 * q0 + q1 * q1;
  float ssk = k0v * k0v + k1v * k1v;
#pragma unroll
  for (int m = 1; m < 64; m <<= 1) {
    ssq += __shfl_xor(ssq, m);
    ssk += __shfl_xor(ssk, m);
  }
  float xq = ssq + 1e-12f;
  float rq = rsqrtf(xq);
  rq = rq * (1.5f - 0.5f * xq * rq * rq);
  float xk = ssk + 1e-12f;
  float rk = rsqrtf(xk);
  rk = rk * (1.5f - 0.5f * xk * rk * rk);
  rq *= 0.08838834764831845f;  // DK^-0.5
  size_t oo = (size_t)bl * KD_ + gc;
  *reinterpret_cast<float2*>(qhat + oo) = make_float2(q0 * rq, q1 * rq);
  *reinterpret_cast<float2*>(khat + oo) = make_float2(k0v * rk, k1v * rk);
}

// ---------------------------------------------------------------------------
// causal conv(4) + SiLU for v (from merged yvg[M][3072], v = cols 0-1535)
// ---------------------------------------------------------------------------
__global__ void conv_v_kernel(const float* __restrict__ yvg, const float* __restrict__ cwv,
                              float* __restrict__ v) {
  int idx = blockIdx.x * 256 + threadIdx.x;
  int c = idx % VD_;
  int bl = idx / VD_;
  int l = bl % L_;
  float w[KS_];
#pragma unroll
  for (int j = 0; j < KS_; j++) w[j] = cwv[(size_t)c * KS_ + j];
  float acc = 0;
#pragma unroll
  for (int j = 0; j < KS_; j++) {
    int ll = l - (KS_ - 1) + j;
    if (ll >= 0) acc = fmaf(yvg[(size_t)(bl - l + ll) * VD2_ + c], w[j], acc);
  }
  v[idx] = silu_f(acc);
}

// ---------------------------------------------------------------------------
// Coefficient precompute per 8-step block (T=8 closed form).
// Record (96 floats): [0..7]=LAM_t (cumulative decay incl step t)
//   [8..35]  = Gt (t>j):  D_tj * (k_t.k_j), idx = t(t-1)/2 + j
//   [36..71] = Pt (t>=j): D_tj * (q_t.k_j), idx = t(t+1)/2 + j  (D_tt = 1)
//   [72..79] = D8_j = suffix decay product (D8_7 = 1)
// D computed via suffix-product recurrence (NO reciprocals: underflow-safe).
// One wave per (bh, blk8): 1536 waves.
// ---------------------------------------------------------------------------
__global__ __launch_bounds__(256) void gp2_kernel(const float* __restrict__ qhat,
                                                  const float* __restrict__ khat,
                                                  const float* __restrict__ eg_t,
                                                  float* __restrict__ gp) {
  const int W = (blockIdx.x << 2) + (threadIdx.x >> 6);  // 0..1535
  const int lane = threadIdx.x & 63;
  const int blk = W & 127;
  const int bh = W >> 7;
  const int b = bh / H_, h = bh % H_;
  const int t0 = blk * 8;
  const size_t base = (size_t)(b * L_ + t0) * KD_ + h * DK_ + 2 * lane;
  float2 k[8], q[8];
#pragma unroll
  for (int t = 0; t < 8; t++) {
    k[t] = *reinterpret_cast<const float2*>(khat + base + (size_t)t * KD_);
    q[t] = *reinterpret_cast<const float2*>(qhat + base + (size_t)t * KD_);
  }
  float g[28], p[36];
#pragma unroll
  for (int t = 1; t < 8; t++)
#pragma unroll
    for (int j = 0; j < t; j++)
      g[t * (t - 1) / 2 + j] = k[t].x * k[j].x + k[t].y * k[j].y;
#pragma unroll
  for (int t = 0; t < 8; t++)
#pragma unroll
    for (int j = 0; j <= t; j++)
      p[t * (t + 1) / 2 + j] = q[t].x * k[j].x + q[t].y * k[j].y;
#pragma unroll
  for (int m = 1; m < 64; m <<= 1) {
#pragma unroll
    for (int i = 0; i < 28; i++) g[i] += __shfl_xor(g[i], m);
#pragma unroll
    for (int i = 0; i < 36; i++) p[i] += __shfl_xor(p[i], m);
  }
  const float* egp = eg_t + (size_t)bh * L_ + t0;
  float lam[8], LAM[8];
#pragma unroll
  for (int t = 0; t < 8; t++) lam[t] = egp[t];
  LAM[0] = lam[0];
#pragma unroll
  for (int t = 1; t < 8; t++) LAM[t] = LAM[t - 1] * lam[t];
  float Dm[28];  // D[t][j] = prod_{s=j+1..t} lam[s]
#pragma unroll
  for (int t = 1; t < 8; t++)
#pragma unroll
    for (int j = 0; j < t; j++)
      Dm[t * (t - 1) / 2 + j] =
          (j == t - 1) ? lam[t] : Dm[(t - 1) * (t - 2) / 2 + j] * lam[t];
  if (lane == 0) {
    float* rec = gp + (size_t)W * 96;
#pragma unroll
    for (int t = 0; t < 8; t++) rec[t] = LAM[t];
#pragma unroll
    for (int t = 1; t < 8; t++)
#pragma unroll
      for (int j = 0; j < t; j++) {
        int ix = t * (t - 1) / 2 + j;
        rec[8 + ix] = Dm[ix] * g[ix];
      }
#pragma unroll
    for (int t = 0; t < 8; t++)
#pragma unroll
      for (int j = 0; j <= t; j++) {
        int ix = t * (t + 1) / 2 + j;
        rec[36 + ix] = (j == t) ? p[ix] : Dm[t * (t - 1) / 2 + j] * p[ix];
      }
#pragma unroll
    for (int j = 0; j < 7; j++) rec[72 + j] = Dm[21 + j];  // D(7,j), 7*6/2=21
    rec[79] = 1.0f;
  }
}

// ---------------------------------------------------------------------------
// Recurrent scan v5: LDS-DMA double-buffered 16-step windows + T=8 algebraic
// blocking with precomputed coefficients. One wave/block, 4 cols/wave,
// 16 lanes/col.
// ---------------------------------------------------------------------------
__global__ __launch_bounds__(64) void scan_kernel(
    const float* __restrict__ qhat, const float* __restrict__ khat,
    const float* __restrict__ vconv, const float* __restrict__ beta_t,
    const float* __restrict__ gp,
    float* __restrict__ o_scan, float* __restrict__ S_out) {
  __shared__ __attribute__((aligned(16))) float kq[2][16][256];  // [buf][t][k|q]
  __shared__ __attribute__((aligned(16))) float scv[2][16][4];   // v per (t,colgrp)
  __shared__ __attribute__((aligned(16))) float scb[2][64];      // beta (first 16 used)
  __shared__ __attribute__((aligned(16))) float gps[2][192];     // 2 blk8 records

  const int lane = threadIdx.x & 63;
  // XCD-bijective swizzle: 768 blocks = 8 XCD x 96
  const int wg = blockIdx.x;
  const int virt = (wg & 7) * 96 + (wg >> 3);
  const int bh = virt >> 6;
  const int tile = virt & 63;
  const int b = bh / H_, h = bh % H_;
  const int grp = lane >> 4;
  const int lsub = lane & 15;
  const int col = tile * 4 + grp;

  const float* kbase = khat + (size_t)b * L_ * KD_ + h * DK_;
  const float* qbase = qhat + (size_t)b * L_ * KD_ + h * DK_;
  const float* vbase = vconv + (size_t)b * L_ * VD_ + h * DV_ + tile * 4;
  const float* bp = beta_t + (size_t)bh * L_;
  const float* gpb = gp + (size_t)bh * 128 * 96;
  float* op = o_scan + (size_t)b * L_ * VD_ + h * DV_ + col;

  float S[8];
#pragma unroll
  for (int i = 0; i < 8; i++) S[i] = 0.0f;

  const int sl = lane & 31;
  const int vt = lane >> 2, vc = lane & 3;

  // 21 DMA ops per window: 16 kq rows + v + beta + 3 gp
#define STAGE(W, BB)                                                                   \
  do {                                                                                 \
    const int _t0 = (W) * 16;                                                          \
    _Pragma("unroll") for (int _j = 0; _j < 16; _j++) {                                \
      const float* _src = (lane < 32) ? (kbase + (size_t)(_t0 + _j) * KD_ + sl * 4)    \
                                      : (qbase + (size_t)(_t0 + _j) * KD_ + sl * 4);   \
      gl_lds16(_src, &kq[BB][_j][0]);                                                  \
    }                                                                                  \
    gl_lds4(vbase + (size_t)(_t0 + vt) * VD_ + vc, &scv[BB][0][0]);                    \
    gl_lds4(bp + _t0 + (lane & 15), &scb[BB][0]);                                      \
    gl_lds4(gpb + (size_t)(W) * 192 + lane, &gps[BB][0]);                              \
    gl_lds4(gpb + (size_t)(W) * 192 + 64 + lane, &gps[BB][64]);                        \
    gl_lds4(gpb + (size_t)(W) * 192 + 128 + lane, &gps[BB][128]);                      \
  } while (0)

#define DOT8(L4, H4) \
  ((fmaf(S[0], (L4).x, S[1] * (L4).y) + fmaf(S[2], (L4).z, S[3] * (L4).w)) + \
   (fmaf(S[4], (H4).x, S[5] * (H4).y) + fmaf(S[6], (H4).z, S[7] * (H4).w)))

  STAGE(0, 0);
  STAGE(1, 1);
  asm volatile("s_waitcnt vmcnt(21)" ::: "memory");  // window 0 ready
  __builtin_amdgcn_sched_barrier(0);

  int cur = 0;
  for (int w = 0; w < L_ / 16; ++w) {
    const int t0 = w * 16;
#pragma unroll
    for (int sb = 0; sb < 2; ++sb) {
      const int j0 = sb * 8;
      const int co = sb * 96;  // coefficient record base in gps
      float4 kl[8], kh[8];
      float a[8], bq[8];
#pragma unroll
      for (int t = 0; t < 8; t++) {
        kl[t] = *reinterpret_cast<const float4*>(&kq[cur][j0 + t][lsub * 4]);
        kh[t] = *reinterpret_cast<const float4*>(&kq[cur][j0 + t][64 + lsub * 4]);
        float4 ql = *reinterpret_cast<const float4*>(&kq[cur][j0 + t][128 + lsub * 4]);
        float4 qh = *reinterpret_cast<const float4*>(&kq[cur][j0 + t][192 + lsub * 4]);
        a[t] = DOT8(kl[t], kh[t]);
        bq[t] = DOT8(ql, qh);
      }
#pragma unroll
      for (int t = 0; t < 8; t++) {
        a[t] = red16(a[t]);
        bq[t] = red16(bq[t]);
      }
      float u[8];
#pragma unroll
      for (int t = 0; t < 8; t++) {
        float lamt = gps[cur][co + t];
        float c = lamt * a[t];
#pragma unroll
        for (int j = 0; j < t; j++)
          c = fmaf(gps[cur][co + 8 + t * (t - 1) / 2 + j], u[j], c);
        u[t] = scb[cur][j0 + t] * (scv[cur][j0 + t][grp] - c);
        float o = lamt * bq[t];
#pragma unroll
        for (int j = 0; j <= t; j++)
          o = fmaf(gps[cur][co + 36 + t * (t + 1) / 2 + j], u[j], o);
        if (lsub == 0) op[(size_t)(t0 + j0 + t) * VD_] = o;
      }
      float wg2[8];
#pragma unroll
      for (int j = 0; j < 8; j++) wg2[j] = gps[cur][co + 72 + j] * u[j];
      const float L8 = gps[cur][co + 7];
      S[0] *= L8; S[1] *= L8; S[2] *= L8; S[3] *= L8;
      S[4] *= L8; S[5] *= L8; S[6] *= L8; S[7] *= L8;
#pragma unroll
      for (int j = 0; j < 8; j++) {
        S[0] = fmaf(kl[j].x, wg2[j], S[0]);
        S[1] = fmaf(kl[j].y, wg2[j], S[1]);
        S[2] = fmaf(kl[j].z, wg2[j], S[2]);
        S[3] = fmaf(kl[j].w, wg2[j], S[3]);
        S[4] = fmaf(kh[j].x, wg2[j], S[4]);
        S[5] = fmaf(kh[j].y, wg2[j], S[5]);
        S[6] = fmaf(kh[j].z, wg2[j], S[6]);
        S[7] = fmaf(kh[j].w, wg2[j], S[7]);
      }
    }
    __builtin_amdgcn_sched_barrier(0);
    if (w < L_ / 16 - 2) {
      STAGE(w + 2, cur);
      // queue (old->new): [stage w+1: 21][stores w: 16][stage w+2: 21]
      asm volatile("s_waitcnt vmcnt(37)" ::: "memory");
    } else {
      asm volatile("s_waitcnt vmcnt(0)" ::: "memory");
    }
    __builtin_amdgcn_sched_barrier(0);
    cur ^= 1;
  }

#pragma unroll
  for (int i = 0; i < 4; i++) {
    S_out[((size_t)bh * DK_ + lsub * 4 + i) * DV_ + col] = S[i];
    S_out[((size_t)bh * DK_ + 64 + lsub * 4 + i) * DV_ + col] = S[4 + i];
  }
#undef STAGE
#undef DOT8
}

// ---------------------------------------------------------------------------
// RMS-norm + norm_w + silu(gate from yvg second half); bf16 out
// ---------------------------------------------------------------------------
__global__ __launch_bounds__(256) void normgate_kernel(
    const float* __restrict__ o_scan, const float* __restrict__ yvg,
    const float* __restrict__ norm_w, unsigned short* __restrict__ o2b) {
  const int lane = threadIdx.x & 63;
  const int widx = (blockIdx.x << 2) + (threadIdx.x >> 6);
  const int h = widx % H_;
  const int bl = widx / H_;
  size_t base = (size_t)bl * VD_ + h * DV_ + (lane << 2);
  size_t gbase = (size_t)bl * VD2_ + VD_ + h * DV_ + (lane << 2);
  float4 o4 = *reinterpret_cast<const float4*>(o_scan + base);
  float ss = o4.x * o4.x + o4.y * o4.y + o4.z * o4.z + o4.w * o4.w;
#pragma unroll
  for (int m = 1; m < 64; m <<= 1) ss += __shfl_xor(ss, m);
  float x = ss * (1.0f / DV_) + 1e-5f;
  float r = rsqrtf(x);
  r = r * (1.5f - 0.5f * x * r * r);
  float4 g4 = *reinterpret_cast<const float4*>(yvg + gbase);
  float4 nw = *reinterpret_cast<const float4*>(norm_w + (lane << 2));
  ushort4 out;
  out.x = f2bf(o4.x * r * nw.x * silu_f(g4.x));
  out.y = f2bf(o4.y * r * nw.y * silu_f(g4.y));
  out.z = f2bf(o4.z * r * nw.z * silu_f(g4.z));
  out.w = f2bf(o4.w * r * nw.w * silu_f(g4.w));
  *reinterpret_cast<ushort4*>(o2b + base) = out;
}

// ---------------------------------------------------------------------------
extern "C" void kernel_launch(void* const* d_in, const int* in_sizes, int n_in,
                              void* d_out, int out_size, void* d_ws, size_t ws_size,
                              hipStream_t stream) {
  const float* x = (const float*)d_in[0];
  const float* Wq = (const float*)d_in[1];
  const float* Wk = (const float*)d_in[2];
  const float* Wv = (const float*)d_in[3];
  const float* Wb = (const float*)d_in[4];
  const float* Wa = (const float*)d_in[5];
  const float* A_log = (const float*)d_in[6];
  const float* dt_bias = (const float*)d_in[7];
  const float* conv_q = (const float*)d_in[8];
  const float* conv_k = (const float*)d_in[9];
  const float* conv_v = (const float*)d_in[10];
  const float* Wg = (const float*)d_in[11];
  const float* norm_w = (const float*)d_in[12];
  const float* Wo = (const float*)d_in[13];

  float* ws = (float*)d_ws;
  const size_t szQK = (size_t)B_ * L_ * KD_;   // 1572864
  const size_t szV = (size_t)B_ * L_ * VD_;    // 3145728
  const size_t szH = (size_t)B_ * L_ * H_;     // 12288
  const size_t szX = (size_t)B_ * L_ * D_;     // 2097152
  const size_t szQK2 = (size_t)B_ * L_ * KD2_; // 3145728
  const size_t szV2 = (size_t)B_ * L_ * VD2_;  // 6291456
  const size_t szGP = (size_t)B_ * H_ * (L_ / 8) * 96;  // 147456

  float* yqk = ws;                    // [M][1536]
  float* yvg = yqk + szQK2;           // [M][3072]
  float* yba = yvg + szV2;            // [M][12]
  float* beta_t = yba + 12 * B_ * L_; // [B,H,L]
  float* eg_t = beta_t + szH;
  float* qhat = eg_t + szH;           // [M][KD]
  float* khat = qhat + szQK;
  float* vconv = khat + szQK;         // [M][VD]
  float* gp = vconv + szV;            // [B*H][128][96]
  float* Wba = gp + szGP;             // [1024][12]
  unsigned short* xb = (unsigned short*)(Wba + (size_t)D_ * 12);
  unsigned short* Wqkt = xb + szX;                        // [1536][1024]
  unsigned short* Wvgt = Wqkt + (size_t)KD2_ * D_;        // [3072][1024]
  unsigned short* Wot = Wvgt + (size_t)VD2_ * D_;         // [1024][1536]
  // aliases (lifetimes disjoint):
  float* o_scan = yqk;                         // [M][VD] over yqk
  unsigned short* o2b = (unsigned short*)yvg;  // [M][VD] bf16 over yvg v-half

  float* o_out = (float*)d_out;
  float* S_out = o_out + (size_t)B_ * L_ * D_;

  const int M = B_ * L_;  // 2048

  // cast / transpose-cast / concat
  cast_bf16_kernel<<<(szX / 4 + 255) / 256, 256, 0, stream>>>(x, xb, szX / 4);
  tcast_kernel<<<dim3(KD_ / 64, D_ / 64), 256, 0, stream>>>(Wq, Wqkt, D_, KD_);
  tcast_kernel<<<dim3(KD_ / 64, D_ / 64), 256, 0, stream>>>(Wk, Wqkt + (size_t)KD_ * D_, D_, KD_);
  tcast_kernel<<<dim3(VD_ / 64, D_ / 64), 256, 0, stream>>>(Wv, Wvgt, D_, VD_);
  tcast_kernel<<<dim3(VD_ / 64, D_ / 64), 256, 0, stream>>>(Wg, Wvgt + (size_t)VD_ * D_, D_, VD_);
  tcast_kernel<<<dim3(D_ / 64, VD_ / 64), 256, 0, stream>>>(Wo, Wot, VD_, D_);
  concat_ba_kernel<<<(D_ * 12 + 255) / 256, 256, 0, stream>>>(Wb, Wa, Wba);

  // merged projections
  mfma_gemm<<<dim3(KD2_ / 128, M / 128), 256, 0, stream>>>(xb, Wqkt, yqk, M, KD2_, D_);
  mfma_gemm<<<dim3(VD2_ / 128, M / 128), 256, 0, stream>>>(xb, Wvgt, yvg, M, VD2_, D_);
  sgemm64<<<dim3(1, M / 64), 256, 0, stream>>>(x, Wba, yba, M, 12, D_);

  // pointwise
  ba_kernel<<<(B_ * L_ * H_ + 255) / 256, 256, 0, stream>>>(yba, A_log, dt_bias, beta_t, eg_t);
  conv_qk_kernel<<<(B_ * L_ * H_) / 4, 256, 0, stream>>>(yqk, conv_q, conv_k, qhat, khat);
  conv_v_kernel<<<(B_ * L_ * VD_) / 256, 256, 0, stream>>>(yvg, conv_v, vconv);
  gp2_kernel<<<(B_ * H_ * (L_ / 8)) / 4, 256, 0, stream>>>(qhat, khat, eg_t, gp);

  // recurrent scan
  scan_kernel<<<B_ * H_ * 64, 64, 0, stream>>>(qhat, khat, vconv, beta_t, gp,
                                               o_scan, S_out);

  // output norm/gate + final projection
  normgate_kernel<<<(B_ * L_ * H_) / 4, 256, 0, stream>>>(o_scan, yvg, norm_w, o2b);
  mfma_gemm<<<dim3(D_ / 128, M / 128), 256, 0, stream>>>(o2b, Wot, o_out, M, D_, VD_);
}

// Round 11
// 414.106 us; speedup vs baseline: 1.3570x; 1.3570x over previous
//
#include <hip/hip_runtime.h>

#define B_ 2
#define L_ 1024
#define D_ 1024
#define H_ 6
#define DK_ 128
#define DV_ 256
#define KD_ 768
#define VD_ 1536
#define KS_ 4
#define NALL_ 4736   // merged projection width: q(768)|k(768)|v(1536)|g(1536)|b(6)|a(6)|pad
#define NB0_ 4608    // b columns start
#define NA0_ 4614    // a columns start
#define NV0_ 1536    // v columns start
#define NG0_ 3072    // g columns start

using bf16x8 = __attribute__((ext_vector_type(8))) short;
using u16x8 = __attribute__((ext_vector_type(8))) unsigned short;
using f32x4 = __attribute__((ext_vector_type(4))) float;

__device__ __forceinline__ float silu_f(float x) { return x / (1.0f + expf(-x)); }

__device__ __forceinline__ unsigned short f2bf(float f) {
  unsigned int u = __float_as_uint(f);
  u = (u + 0x7fffu + ((u >> 16) & 1u)) >> 16;
  return (unsigned short)u;
}

__device__ __forceinline__ void gl_lds16(const void* g, void* l) {
  __builtin_amdgcn_global_load_lds((const __attribute__((address_space(1))) unsigned int*)g,
                                   (__attribute__((address_space(3))) unsigned int*)l, 16, 0, 0);
}
__device__ __forceinline__ void gl_lds4(const void* g, void* l) {
  __builtin_amdgcn_global_load_lds((const __attribute__((address_space(1))) unsigned int*)g,
                                   (__attribute__((address_space(3))) unsigned int*)l, 4, 0, 0);
}

template <int CTRL>
__device__ __forceinline__ float dpp_add(float x) {
  int y = __builtin_amdgcn_mov_dpp(__float_as_int(x), CTRL, 0xF, 0xF, true);
  return x + __int_as_float(y);
}
// full 16-lane-group sum via DPP butterfly: masks {1,2,7,15} span {0..15}
__device__ __forceinline__ float red16(float x) {
  x = dpp_add<0xB1>(x);   // quad_perm xor 1
  x = dpp_add<0x4E>(x);   // quad_perm xor 2
  x = dpp_add<0x141>(x);  // row_half_mirror xor 7
  x = dpp_add<0x140>(x);  // row_mirror xor 15
  return x;
}

// ---------------------------------------------------------------------------
__global__ void cast_bf16_kernel(const float* __restrict__ in, unsigned short* __restrict__ out,
                                 int n4) {
  int i = blockIdx.x * 256 + threadIdx.x;
  if (i >= n4) return;
  float4 v = *reinterpret_cast<const float4*>(in + (size_t)i * 4);
  ushort4 o;
  o.x = f2bf(v.x);
  o.y = f2bf(v.y);
  o.z = f2bf(v.z);
  o.w = f2bf(v.w);
  *reinterpret_cast<ushort4*>(out + (size_t)i * 4) = o;
}

// ---------------------------------------------------------------------------
// transpose + cast: W fp32 [K][N] -> Wt bf16 [N][K].  64x64 tiles.
// ---------------------------------------------------------------------------
__global__ __launch_bounds__(256) void tcast_kernel(const float* __restrict__ W,
                                                    unsigned short* __restrict__ Wt,
                                                    int K, int N) {
  __shared__ unsigned short T[64][72];
  const int tid = threadIdx.x;
  const int k0 = blockIdx.y * 64, n0 = blockIdx.x * 64;
  const int c4 = (tid & 15) * 4, r = tid >> 4;
#pragma unroll
  for (int j = 0; j < 4; j++) {
    int row = r + j * 16;
    float4 w = *reinterpret_cast<const float4*>(W + (size_t)(k0 + row) * N + n0 + c4);
    T[c4 + 0][row] = f2bf(w.x);
    T[c4 + 1][row] = f2bf(w.y);
    T[c4 + 2][row] = f2bf(w.z);
    T[c4 + 3][row] = f2bf(w.w);
  }
  __syncthreads();
#pragma unroll
  for (int j = 0; j < 4; j++) {
    int nr = r + j * 16;
    ushort4 o;
    o.x = T[nr][c4 + 0];
    o.y = T[nr][c4 + 1];
    o.z = T[nr][c4 + 2];
    o.w = T[nr][c4 + 3];
    *reinterpret_cast<ushort4*>(Wt + (size_t)(n0 + nr) * K + k0 + c4) = o;
  }
}

// ---------------------------------------------------------------------------
// rows 4608..4735 of Wall_t: b|a weights transposed + zero pad.
// ---------------------------------------------------------------------------
__global__ void wba_kernel(const float* __restrict__ Wb, const float* __restrict__ Wa,
                           unsigned short* __restrict__ Wt) {
  int idx = blockIdx.x * 256 + threadIdx.x;  // 128*1024
  if (idx >= 128 * 1024) return;
  int r = idx >> 10, k = idx & 1023;
  float v = 0.0f;
  if (r < 6) v = Wb[k * 6 + r];
  else if (r < 12) v = Wa[k * 6 + (r - 6)];
  Wt[(size_t)(NB0_ + r) * D_ + k] = f2bf(v);
}

// ---------------------------------------------------------------------------
// bf16 MFMA GEMM (m97 structure, gl_lds staging, involution chunk-XOR)
// ---------------------------------------------------------------------------
__global__ __launch_bounds__(256) void mfma_gemm(const unsigned short* __restrict__ A,
                                                 const unsigned short* __restrict__ Bt,
                                                 float* __restrict__ C,
                                                 int M, int N, int K) {
  __shared__ __attribute__((aligned(16))) unsigned short As[128][32];
  __shared__ __attribute__((aligned(16))) unsigned short Bs[128][32];
  const int tid = threadIdx.x;
  const int wave = tid >> 6, lane = tid & 63;
  const int wm = wave >> 1, wn = wave & 1;
  const int m0 = blockIdx.y * 128, n0 = blockIdx.x * 128;
  const int lrow = lane >> 4;
  const int lcol = lane & 15;
  const int sr = lane >> 2;
  const int sc = lane & 3;

  f32x4 acc[4][4];
#pragma unroll
  for (int i = 0; i < 4; i++)
#pragma unroll
    for (int j = 0; j < 4; j++) acc[i][j] = f32x4{0.f, 0.f, 0.f, 0.f};

  const int Ra = wave * 32;

  for (int k0 = 0; k0 < K; k0 += 32) {
#pragma unroll
    for (int half = 0; half < 2; half++) {
      int r = Ra + half * 16 + sr;
      int ch = sc ^ ((r >> 1) & 3);
      gl_lds16(A + (size_t)(m0 + r) * K + k0 + ch * 8, &As[Ra + half * 16][0]);
      gl_lds16(Bt + (size_t)(n0 + r) * K + k0 + ch * 8, &Bs[Ra + half * 16][0]);
    }
    __syncthreads();
    bf16x8 af[4], bfr[4];
#pragma unroll
    for (int mr = 0; mr < 4; mr++) {
      int row = wm * 64 + mr * 16 + lcol;
      af[mr] = *reinterpret_cast<const bf16x8*>(&As[row][(lrow ^ ((row >> 1) & 3)) * 8]);
    }
#pragma unroll
    for (int nr = 0; nr < 4; nr++) {
      int row = wn * 64 + nr * 16 + lcol;
      bfr[nr] = *reinterpret_cast<const bf16x8*>(&Bs[row][(lrow ^ ((row >> 1) & 3)) * 8]);
    }
#pragma unroll
    for (int mr = 0; mr < 4; mr++)
#pragma unroll
      for (int nr = 0; nr < 4; nr++)
        acc[mr][nr] = __builtin_amdgcn_mfma_f32_16x16x32_bf16(af[mr], bfr[nr], acc[mr][nr], 0, 0, 0);
    __syncthreads();
  }

#pragma unroll
  for (int mr = 0; mr < 4; mr++) {
    int row = m0 + wm * 64 + mr * 16 + lrow * 4;
#pragma unroll
    for (int nr = 0; nr < 4; nr++) {
      int col = n0 + wn * 64 + nr * 16 + lcol;
#pragma unroll
      for (int r = 0; r < 4; r++) C[(size_t)(row + r) * N + col] = acc[mr][nr][r];
    }
  }
}

// ---------------------------------------------------------------------------
// beta / decay from yall cols [4608..4620)
// ---------------------------------------------------------------------------
__global__ void ba_kernel(const float* __restrict__ yall,
                          const float* __restrict__ A_log, const float* __restrict__ dt_bias,
                          float* __restrict__ beta_t, float* __restrict__ eg_t) {
  int i = blockIdx.x * 256 + threadIdx.x;
  if (i >= B_ * L_ * H_) return;
  int h = i % H_, bl = i / H_;
  int l = bl % L_, b = bl / L_;
  float yb = yall[(size_t)bl * NALL_ + NB0_ + h];
  float ya = yall[(size_t)bl * NALL_ + NA0_ + h];
  float beta = 1.0f / (1.0f + expf(-yb));
  float z = ya + dt_bias[h];
  float sp = (z > 20.0f) ? z : log1pf(expf(z));
  float g = -expf(A_log[h]) * sp;
  size_t o = ((size_t)b * H_ + h) * L_ + l;
  beta_t[o] = beta;
  eg_t[o] = expf(g);
}

// ---------------------------------------------------------------------------
// causal conv(4) + SiLU + L2-norm for q,k (yall cols 0..767 | 768..1535)
// ---------------------------------------------------------------------------
__global__ __launch_bounds__(256) void conv_qk_kernel(
    const float* __restrict__ yall,
    const float* __restrict__ cwq, const float* __restrict__ cwk,
    float* __restrict__ qhat, float* __restrict__ khat) {
  const int lane = threadIdx.x & 63;
  const int widx = (blockIdx.x << 2) + (threadIdx.x >> 6);
  const int h = widx % H_;
  const int bl = widx / H_;
  const int l = bl % L_;
  const int b = bl / L_;
  const int ch = lane << 1;
  const int gc = h * DK_ + ch;

  float wq0[KS_], wq1[KS_], wk0[KS_], wk1[KS_];
#pragma unroll
  for (int j = 0; j < KS_; j++) {
    wq0[j] = cwq[(size_t)gc * KS_ + j];
    wq1[j] = cwq[(size_t)(gc + 1) * KS_ + j];
    wk0[j] = cwk[(size_t)gc * KS_ + j];
    wk1[j] = cwk[(size_t)(gc + 1) * KS_ + j];
  }
  float aq0 = 0, aq1 = 0, ak0 = 0, ak1 = 0;
#pragma unroll
  for (int j = 0; j < KS_; j++) {
    int ll = l - (KS_ - 1) + j;
    if (ll >= 0) {
      const size_t off = (size_t)(b * L_ + ll) * NALL_ + gc;
      float2 tq = *reinterpret_cast<const float2*>(yall + off);
      float2 tk = *reinterpret_cast<const float2*>(yall + off + 768);
      aq0 = fmaf(tq.x, wq0[j], aq0);
      aq1 = fmaf(tq.y, wq1[j], aq1);
      ak0 = fmaf(tk.x, wk0[j], ak0);
      ak1 = fmaf(tk.y, wk1[j], ak1);
    }
  }
  float q0 = silu_f(aq0), q1 = silu_f(aq1);
  float k0v = silu_f(ak0), k1v = silu_f(ak1);
  float ssq = q0 * q0 + q1 * q1;
  float ssk = k0v * k0v + k1v * k1v;
#pragma unroll
  for (int m = 1; m < 64; m <<= 1) {
    ssq += __shfl_xor(ssq, m);
    ssk += __shfl_xor(ssk, m);
  }
  float xq = ssq + 1e-12f;
  float rq = rsqrtf(xq);
  rq = rq * (1.5f - 0.5f * xq * rq * rq);
  float xk = ssk + 1e-12f;
  float rk = rsqrtf(xk);
  rk = rk * (1.5f - 0.5f * xk * rk * rk);
  rq *= 0.08838834764831845f;  // DK^-0.5
  size_t oo = (size_t)bl * KD_ + gc;
  *reinterpret_cast<float2*>(qhat + oo) = make_float2(q0 * rq, q1 * rq);
  *reinterpret_cast<float2*>(khat + oo) = make_float2(k0v * rk, k1v * rk);
}

// ---------------------------------------------------------------------------
// causal conv(4) + SiLU for v (yall cols 1536..3071)
// ---------------------------------------------------------------------------
__global__ void conv_v_kernel(const float* __restrict__ yall, const float* __restrict__ cwv,
                              float* __restrict__ v) {
  int idx = blockIdx.x * 256 + threadIdx.x;
  int c = idx % VD_;
  int bl = idx / VD_;
  int l = bl % L_;
  float w[KS_];
#pragma unroll
  for (int j = 0; j < KS_; j++) w[j] = cwv[(size_t)c * KS_ + j];
  float acc = 0;
#pragma unroll
  for (int j = 0; j < KS_; j++) {
    int ll = l - (KS_ - 1) + j;
    if (ll >= 0) acc = fmaf(yall[(size_t)(bl - l + ll) * NALL_ + NV0_ + c], w[j], acc);
  }
  v[idx] = silu_f(acc);
}

// ---------------------------------------------------------------------------
// Gram precompute per 4-step block: [G21,G31,G32,G41,G42,G43,
//  P21,P31,P32,P41,P42,P43, P11,P22,P33,P44]  (G=k_i.k_j, P=q_i.k_j)
// ---------------------------------------------------------------------------
__global__ __launch_bounds__(256) void gp_kernel(const float* __restrict__ qhat,
                                                 const float* __restrict__ khat,
                                                 float* __restrict__ gp) {
  const int W = (blockIdx.x << 2) + (threadIdx.x >> 6);  // 0..3071
  const int lane = threadIdx.x & 63;
  const int blk = W & 255;
  const int bh = W >> 8;
  const int b = bh / H_, h = bh % H_;
  const int t0 = blk * 4;
  const size_t base = (size_t)(b * L_ + t0) * KD_ + h * DK_ + 2 * lane;
  float2 k1 = *reinterpret_cast<const float2*>(khat + base);
  float2 k2 = *reinterpret_cast<const float2*>(khat + base + KD_);
  float2 k3 = *reinterpret_cast<const float2*>(khat + base + 2 * KD_);
  float2 k4 = *reinterpret_cast<const float2*>(khat + base + 3 * KD_);
  float2 q1 = *reinterpret_cast<const float2*>(qhat + base);
  float2 q2 = *reinterpret_cast<const float2*>(qhat + base + KD_);
  float2 q3 = *reinterpret_cast<const float2*>(qhat + base + 2 * KD_);
  float2 q4 = *reinterpret_cast<const float2*>(qhat + base + 3 * KD_);
  float g21 = k2.x * k1.x + k2.y * k1.y;
  float g31 = k3.x * k1.x + k3.y * k1.y;
  float g32 = k3.x * k2.x + k3.y * k2.y;
  float g41 = k4.x * k1.x + k4.y * k1.y;
  float g42 = k4.x * k2.x + k4.y * k2.y;
  float g43 = k4.x * k3.x + k4.y * k3.y;
  float p21 = q2.x * k1.x + q2.y * k1.y;
  float p31 = q3.x * k1.x + q3.y * k1.y;
  float p32 = q3.x * k2.x + q3.y * k2.y;
  float p41 = q4.x * k1.x + q4.y * k1.y;
  float p42 = q4.x * k2.x + q4.y * k2.y;
  float p43 = q4.x * k3.x + q4.y * k3.y;
  float p11 = q1.x * k1.x + q1.y * k1.y;
  float p22 = q2.x * k2.x + q2.y * k2.y;
  float p33 = q3.x * k3.x + q3.y * k3.y;
  float p44 = q4.x * k4.x + q4.y * k4.y;
#pragma unroll
  for (int m = 1; m < 64; m <<= 1) {
    g21 += __shfl_xor(g21, m); g31 += __shfl_xor(g31, m); g32 += __shfl_xor(g32, m);
    g41 += __shfl_xor(g41, m); g42 += __shfl_xor(g42, m); g43 += __shfl_xor(g43, m);
    p21 += __shfl_xor(p21, m); p31 += __shfl_xor(p31, m); p32 += __shfl_xor(p32, m);
    p41 += __shfl_xor(p41, m); p42 += __shfl_xor(p42, m); p43 += __shfl_xor(p43, m);
    p11 += __shfl_xor(p11, m); p22 += __shfl_xor(p22, m); p33 += __shfl_xor(p33, m);
    p44 += __shfl_xor(p44, m);
  }
  // select-tree: lane i (0..15) holds value i
  const bool l0 = lane & 1, l1 = lane & 2, l2 = lane & 4, l3 = lane & 8;
  float s00 = l0 ? g31 : g21, s01 = l0 ? g41 : g32, s02 = l0 ? g43 : g42, s03 = l0 ? p31 : p21;
  float s04 = l0 ? p41 : p32, s05 = l0 ? p43 : p42, s06 = l0 ? p22 : p11, s07 = l0 ? p44 : p33;
  float s10 = l1 ? s01 : s00, s11 = l1 ? s03 : s02, s12 = l1 ? s05 : s04, s13 = l1 ? s07 : s06;
  float s20 = l2 ? s11 : s10, s21 = l2 ? s13 : s12;
  float out = l3 ? s21 : s20;
  if (lane < 16) gp[((size_t)bh * 256 + blk) * 16 + lane] = out;
}

// ---------------------------------------------------------------------------
// Recurrent scan (measured-best T=4): LDS-DMA double-buffered 16-step windows
// + T=4 algebraic blocking. One wave/block, 4 cols/wave, 16 lanes/col.
// ---------------------------------------------------------------------------
__global__ __launch_bounds__(64) void scan_kernel(
    const float* __restrict__ qhat, const float* __restrict__ khat,
    const float* __restrict__ vconv, const float* __restrict__ beta_t,
    const float* __restrict__ eg_t, const float* __restrict__ gp,
    float* __restrict__ o_scan, float* __restrict__ S_out) {
  __shared__ __attribute__((aligned(16))) float kq[2][16][256];  // [buf][t][k|q]
  __shared__ __attribute__((aligned(16))) float scv[2][16][4];   // v per (t,colgrp)
  __shared__ __attribute__((aligned(16))) float sce[2][4][16];   // rows: eg, bt, dup, dup
  __shared__ __attribute__((aligned(16))) float gps[2][4][16];   // 4 sub-blocks x 16 gram vals

  const int lane = threadIdx.x & 63;
  // XCD-bijective swizzle: 768 blocks = 8 XCD x 96
  const int wg = blockIdx.x;
  const int virt = (wg & 7) * 96 + (wg >> 3);
  const int bh = virt >> 6;
  const int tile = virt & 63;
  const int b = bh / H_, h = bh % H_;
  const int grp = lane >> 4;
  const int lsub = lane & 15;
  const int col = tile * 4 + grp;

  const float* kbase = khat + (size_t)b * L_ * KD_ + h * DK_;
  const float* qbase = qhat + (size_t)b * L_ * KD_ + h * DK_;
  const float* vbase = vconv + (size_t)b * L_ * VD_ + h * DV_ + tile * 4;
  const float* egp = eg_t + (size_t)bh * L_;
  const float* bp = beta_t + (size_t)bh * L_;
  const float* gpb = gp + (size_t)bh * 256 * 16;
  float* op = o_scan + (size_t)b * L_ * VD_ + h * DV_ + col;

  float S[8];
#pragma unroll
  for (int i = 0; i < 8; i++) S[i] = 0.0f;

  const int sl = lane & 31;
  const int vt = lane >> 2, vc = lane & 3;
  const int et = lane & 15, ej = lane >> 4;
  const float* ebase = (ej == 0) ? egp : bp;  // rows 1..3 all bt (dup harmless)

  // 19 DMA ops per window
#define STAGE(W, BB)                                                                   \
  do {                                                                                 \
    const int _t0 = (W) * 16;                                                          \
    _Pragma("unroll") for (int _j = 0; _j < 16; _j++) {                                \
      const float* _src = (lane < 32) ? (kbase + (size_t)(_t0 + _j) * KD_ + sl * 4)    \
                                      : (qbase + (size_t)(_t0 + _j) * KD_ + sl * 4);   \
      gl_lds16(_src, &kq[BB][_j][0]);                                                  \
    }                                                                                  \
    gl_lds4(vbase + (size_t)(_t0 + vt) * VD_ + vc, &scv[BB][0][0]);                    \
    gl_lds4(ebase + _t0 + et, &sce[BB][0][0]);                                         \
    gl_lds4(gpb + (size_t)(W) * 64 + lane, &gps[BB][0][0]);                            \
  } while (0)

#define DOT8(L4, H4) \
  ((fmaf(S[0], (L4).x, S[1] * (L4).y) + fmaf(S[2], (L4).z, S[3] * (L4).w)) + \
   (fmaf(S[4], (H4).x, S[5] * (H4).y) + fmaf(S[6], (H4).z, S[7] * (H4).w)))

  STAGE(0, 0);
  STAGE(1, 1);
  asm volatile("s_waitcnt vmcnt(19)" ::: "memory");  // window 0 ready
  __builtin_amdgcn_sched_barrier(0);

  int cur = 0;
  for (int w = 0; w < L_ / 16; ++w) {
    const int t0 = w * 16;
#pragma unroll
    for (int sb = 0; sb < 4; ++sb) {
      const int j0 = sb * 4;
      float4 k1l = *reinterpret_cast<const float4*>(&kq[cur][j0 + 0][lsub * 4]);
      float4 k1h = *reinterpret_cast<const float4*>(&kq[cur][j0 + 0][64 + lsub * 4]);
      float4 q1l = *reinterpret_cast<const float4*>(&kq[cur][j0 + 0][128 + lsub * 4]);
      float4 q1h = *reinterpret_cast<const float4*>(&kq[cur][j0 + 0][192 + lsub * 4]);
      float4 k2l = *reinterpret_cast<const float4*>(&kq[cur][j0 + 1][lsub * 4]);
      float4 k2h = *reinterpret_cast<const float4*>(&kq[cur][j0 + 1][64 + lsub * 4]);
      float4 q2l = *reinterpret_cast<const float4*>(&kq[cur][j0 + 1][128 + lsub * 4]);
      float4 q2h = *reinterpret_cast<const float4*>(&kq[cur][j0 + 1][192 + lsub * 4]);
      float4 k3l = *reinterpret_cast<const float4*>(&kq[cur][j0 + 2][lsub * 4]);
      float4 k3h = *reinterpret_cast<const float4*>(&kq[cur][j0 + 2][64 + lsub * 4]);
      float4 q3l = *reinterpret_cast<const float4*>(&kq[cur][j0 + 2][128 + lsub * 4]);
      float4 q3h = *reinterpret_cast<const float4*>(&kq[cur][j0 + 2][192 + lsub * 4]);
      float4 k4l = *reinterpret_cast<const float4*>(&kq[cur][j0 + 3][lsub * 4]);
      float4 k4h = *reinterpret_cast<const float4*>(&kq[cur][j0 + 3][64 + lsub * 4]);
      float4 q4l = *reinterpret_cast<const float4*>(&kq[cur][j0 + 3][128 + lsub * 4]);
      float4 q4h = *reinterpret_cast<const float4*>(&kq[cur][j0 + 3][192 + lsub * 4]);
      float v1 = scv[cur][j0 + 0][grp], v2 = scv[cur][j0 + 1][grp];
      float v3 = scv[cur][j0 + 2][grp], v4 = scv[cur][j0 + 3][grp];
      float e1 = sce[cur][0][j0 + 0], e2 = sce[cur][0][j0 + 1];
      float e3 = sce[cur][0][j0 + 2], e4 = sce[cur][0][j0 + 3];
      float bt1 = sce[cur][1][j0 + 0], bt2 = sce[cur][1][j0 + 1];
      float bt3 = sce[cur][1][j0 + 2], bt4 = sce[cur][1][j0 + 3];
      float g21 = gps[cur][sb][0], g31 = gps[cur][sb][1], g32 = gps[cur][sb][2];
      float g41 = gps[cur][sb][3], g42 = gps[cur][sb][4], g43 = gps[cur][sb][5];
      float p21 = gps[cur][sb][6], p31 = gps[cur][sb][7], p32 = gps[cur][sb][8];
      float p41 = gps[cur][sb][9], p42 = gps[cur][sb][10], p43 = gps[cur][sb][11];
      float p11 = gps[cur][sb][12], p22 = gps[cur][sb][13];
      float p33 = gps[cur][sb][14], p44 = gps[cur][sb][15];

      // 8 independent dots vs S0, reduced together (latency amortized 4 steps)
      float a1 = red16(DOT8(k1l, k1h));
      float a2 = red16(DOT8(k2l, k2h));
      float a3 = red16(DOT8(k3l, k3h));
      float a4 = red16(DOT8(k4l, k4h));
      float b1 = red16(DOT8(q1l, q1h));
      float b2 = red16(DOT8(q2l, q2h));
      float b3 = red16(DOT8(q3l, q3h));
      float b4 = red16(DOT8(q4l, q4h));

      // scalar recurrence (exact unroll of the 4-step delta rule)
      float E2 = e1 * e2, E3 = E2 * e3, E4 = E3 * e4;
      float f32v = e3 * e2, f43 = e4 * e3, f432 = e4 * f32v;
      float u1 = (v1 - e1 * a1) * bt1;
      float c2 = fmaf(g21, u1, e1 * a2);
      float u2 = (v2 - e2 * c2) * bt2;
      float c3 = fmaf(g32, u2, fmaf(e2 * g31, u1, E2 * a3));
      float u3 = (v3 - e3 * c3) * bt3;
      float c4 = fmaf(g43, u3, fmaf(e3 * g42, u2, fmaf(f32v * g41, u1, E3 * a4)));
      float u4 = (v4 - e4 * c4) * bt4;
      float o1 = fmaf(p11, u1, e1 * b1);
      float o2 = fmaf(p22, u2, fmaf(e2 * p21, u1, E2 * b2));
      float o3 = fmaf(p33, u3, fmaf(e3 * p32, u2, fmaf(f32v * p31, u1, E3 * b3)));
      float o4 = fmaf(p44, u4,
                      fmaf(e4 * p43, u3, fmaf(f43 * p42, u2, fmaf(f432 * p41, u1, E4 * b4))));
      float w1 = f432 * u1, w2 = f43 * u2, w3 = e4 * u3, w4 = u4;

      // rank-4 state update
      S[0] = fmaf(k4l.x, w4, fmaf(k3l.x, w3, fmaf(k2l.x, w2, fmaf(k1l.x, w1, S[0] * E4))));
      S[1] = fmaf(k4l.y, w4, fmaf(k3l.y, w3, fmaf(k2l.y, w2, fmaf(k1l.y, w1, S[1] * E4))));
      S[2] = fmaf(k4l.z, w4, fmaf(k3l.z, w3, fmaf(k2l.z, w2, fmaf(k1l.z, w1, S[2] * E4))));
      S[3] = fmaf(k4l.w, w4, fmaf(k3l.w, w3, fmaf(k2l.w, w2, fmaf(k1l.w, w1, S[3] * E4))));
      S[4] = fmaf(k4h.x, w4, fmaf(k3h.x, w3, fmaf(k2h.x, w2, fmaf(k1h.x, w1, S[4] * E4))));
      S[5] = fmaf(k4h.y, w4, fmaf(k3h.y, w3, fmaf(k2h.y, w2, fmaf(k1h.y, w1, S[5] * E4))));
      S[6] = fmaf(k4h.z, w4, fmaf(k3h.z, w3, fmaf(k2h.z, w2, fmaf(k1h.z, w1, S[6] * E4))));
      S[7] = fmaf(k4h.w, w4, fmaf(k3h.w, w3, fmaf(k2h.w, w2, fmaf(k1h.w, w1, S[7] * E4))));

      if (lsub == 0) {
        op[(size_t)(t0 + j0 + 0) * VD_] = o1;
        op[(size_t)(t0 + j0 + 1) * VD_] = o2;
        op[(size_t)(t0 + j0 + 2) * VD_] = o3;
        op[(size_t)(t0 + j0 + 3) * VD_] = o4;
      }
    }
    __builtin_amdgcn_sched_barrier(0);
    if (w < L_ / 16 - 2) {
      STAGE(w + 2, cur);
      // queue (old->new): [stage w+1: 19][stores w: 16][stage w+2: 19]
      asm volatile("s_waitcnt vmcnt(35)" ::: "memory");
    } else {
      asm volatile("s_waitcnt vmcnt(0)" ::: "memory");
    }
    __builtin_amdgcn_sched_barrier(0);
    cur ^= 1;
  }

#pragma unroll
  for (int i = 0; i < 4; i++) {
    S_out[((size_t)bh * DK_ + lsub * 4 + i) * DV_ + col] = S[i];
    S_out[((size_t)bh * DK_ + 64 + lsub * 4 + i) * DV_ + col] = S[4 + i];
  }
#undef STAGE
#undef DOT8
}

// ---------------------------------------------------------------------------
// RMS-norm + norm_w + silu(gate from yall cols 3072..4607); bf16 out
// ---------------------------------------------------------------------------
__global__ __launch_bounds__(256) void normgate_kernel(
    const float* __restrict__ o_scan, const float* __restrict__ yall,
    const float* __restrict__ norm_w, unsigned short* __restrict__ o2b) {
  const int lane = threadIdx.x & 63;
  const int widx = (blockIdx.x << 2) + (threadIdx.x >> 6);
  const int h = widx % H_;
  const int bl = widx / H_;
  size_t base = (size_t)bl * VD_ + h * DV_ + (lane << 2);
  size_t gbase = (size_t)bl * NALL_ + NG0_ + h * DV_ + (lane << 2);
  float4 o4 = *reinterpret_cast<const float4*>(o_scan + base);
  float ss = o4.x * o4.x + o4.y * o4.y + o4.z * o4.z + o4.w * o4.w;
#pragma unroll
  for (int m = 1; m < 64; m <<= 1) ss += __shfl_xor(ss, m);
  float x = ss * (1.0f / DV_) + 1e-5f;
  float r = rsqrtf(x);
  r = r * (1.5f - 0.5f * x * r * r);
  float4 g4 = *reinterpret_cast<const float4*>(yall + gbase);
  float4 nw = *reinterpret_cast<const float4*>(norm_w + (lane << 2));
  ushort4 out;
  out.x = f2bf(o4.x * r * nw.x * silu_f(g4.x));
  out.y = f2bf(o4.y * r * nw.y * silu_f(g4.y));
  out.z = f2bf(o4.z * r * nw.z * silu_f(g4.z));
  out.w = f2bf(o4.w * r * nw.w * silu_f(g4.w));
  *reinterpret_cast<ushort4*>(o2b + base) = out;
}

// ---------------------------------------------------------------------------
extern "C" void kernel_launch(void* const* d_in, const int* in_sizes, int n_in,
                              void* d_out, int out_size, void* d_ws, size_t ws_size,
                              hipStream_t stream) {
  const float* x = (const float*)d_in[0];
  const float* Wq = (const float*)d_in[1];
  const float* Wk = (const float*)d_in[2];
  const float* Wv = (const float*)d_in[3];
  const float* Wb = (const float*)d_in[4];
  const float* Wa = (const float*)d_in[5];
  const float* A_log = (const float*)d_in[6];
  const float* dt_bias = (const float*)d_in[7];
  const float* conv_q = (const float*)d_in[8];
  const float* conv_k = (const float*)d_in[9];
  const float* conv_v = (const float*)d_in[10];
  const float* Wg = (const float*)d_in[11];
  const float* norm_w = (const float*)d_in[12];
  const float* Wo = (const float*)d_in[13];

  float* ws = (float*)d_ws;
  const size_t szQK = (size_t)B_ * L_ * KD_;    // 1572864
  const size_t szV = (size_t)B_ * L_ * VD_;     // 3145728
  const size_t szH = (size_t)B_ * L_ * H_;      // 12288
  const size_t szX = (size_t)B_ * L_ * D_;      // 2097152
  const size_t szALL = (size_t)B_ * L_ * NALL_; // 9699328
  const size_t szGP = (size_t)B_ * H_ * (L_ / 4) * 16;  // 49152

  float* yall = ws;                   // [M][4736]
  float* beta_t = yall + szALL;       // [B,H,L]
  float* eg_t = beta_t + szH;
  float* qhat = eg_t + szH;           // [M][KD]
  float* khat = qhat + szQK;
  float* vconv = khat + szQK;         // [M][VD]
  float* gp = vconv + szV;            // [B*H][256][16]
  float* o_scan = gp + szGP;          // [M][VD]
  unsigned short* xb = (unsigned short*)(o_scan + szV);
  unsigned short* Wallt = xb + szX;                      // [4736][1024]
  unsigned short* Wot = Wallt + (size_t)NALL_ * D_;      // [1024][1536]
  // alias (lifetimes disjoint): o2b over vconv (dead after scan)
  unsigned short* o2b = (unsigned short*)vconv;

  float* o_out = (float*)d_out;
  float* S_out = o_out + (size_t)B_ * L_ * D_;

  const int M = B_ * L_;  // 2048

  // cast / weight prep
  cast_bf16_kernel<<<(szX / 4 + 255) / 256, 256, 0, stream>>>(x, xb, szX / 4);
  tcast_kernel<<<dim3(KD_ / 64, D_ / 64), 256, 0, stream>>>(Wq, Wallt, D_, KD_);
  tcast_kernel<<<dim3(KD_ / 64, D_ / 64), 256, 0, stream>>>(Wk, Wallt + (size_t)768 * D_, D_, KD_);
  tcast_kernel<<<dim3(VD_ / 64, D_ / 64), 256, 0, stream>>>(Wv, Wallt + (size_t)NV0_ * D_, D_, VD_);
  tcast_kernel<<<dim3(VD_ / 64, D_ / 64), 256, 0, stream>>>(Wg, Wallt + (size_t)NG0_ * D_, D_, VD_);
  wba_kernel<<<(128 * 1024 + 255) / 256, 256, 0, stream>>>(Wb, Wa, Wallt);
  tcast_kernel<<<dim3(D_ / 64, VD_ / 64), 256, 0, stream>>>(Wo, Wot, VD_, D_);

  // single merged projection GEMM
  mfma_gemm<<<dim3(NALL_ / 128, M / 128), 256, 0, stream>>>(xb, Wallt, yall, M, NALL_, D_);

  // pointwise
  ba_kernel<<<(B_ * L_ * H_ + 255) / 256, 256, 0, stream>>>(yall, A_log, dt_bias, beta_t, eg_t);
  conv_qk_kernel<<<(B_ * L_ * H_) / 4, 256, 0, stream>>>(yall, conv_q, conv_k, qhat, khat);
  conv_v_kernel<<<(B_ * L_ * VD_) / 256, 256, 0, stream>>>(yall, conv_v, vconv);
  gp_kernel<<<(B_ * H_ * (L_ / 4)) / 4, 256, 0, stream>>>(qhat, khat, gp);

  // recurrent scan
  scan_kernel<<<B_ * H_ * 64, 64, 0, stream>>>(qhat, khat, vconv, beta_t, eg_t, gp,
                                               o_scan, S_out);

  // output norm/gate + final projection
  normgate_kernel<<<(B_ * L_ * H_) / 4, 256, 0, stream>>>(o_scan, yall, norm_w, o2b);
  mfma_gemm<<<dim3(D_ / 128, M / 128), 256, 0, stream>>>(o2b, Wot, o_out, M, D_, VD_);
}